// Round 1
// baseline (2424.560 us; speedup 1.0000x reference)
//
#include <hip/hip_runtime.h>
#include <math.h>

#define EPS 1e-5f

// ---------------- Kernel 1: x = LN(dense @ Wd^T, gd, bd) ----------------
// dense: (B,256), Wd: (128,256), x: (B,128). 8 rows per block, 256 threads.
__global__ __launch_bounds__(256) void k_dense_ln(
    const float* __restrict__ dense, const float* __restrict__ Wd,
    const float* __restrict__ gd, const float* __restrict__ bd,
    float* __restrict__ x)
{
    __shared__ float wlds[128][33];   // Wd k-chunk, padded (bank-safe: (33e+k)%32=(e+k)%32)
    __shared__ float dlds[32][9];     // dense chunk transposed [k][row]
    __shared__ float redS[4][4], redQ[4][4];
    const int t = threadIdx.x;
    const int e = t & 127, h = t >> 7;
    const int lane = t & 63, wid = t >> 6;
    const int r0 = blockIdx.x * 8;
    float acc[4] = {0.f, 0.f, 0.f, 0.f};
    for (int kc = 0; kc < 256; kc += 32) {
        for (int f = t; f < 128 * 32; f += 256) {
            int ee = f >> 5, kk = f & 31;
            wlds[ee][kk] = Wd[ee * 256 + kc + kk];
        }
        {
            int rr = t >> 5, kk = t & 31;
            dlds[kk][rr] = dense[(size_t)(r0 + rr) * 256 + kc + kk];
        }
        __syncthreads();
        #pragma unroll
        for (int kk = 0; kk < 32; ++kk) {
            float w = wlds[e][kk];                 // 2-way (free) bank aliasing
            acc[0] += w * dlds[kk][h * 4 + 0];     // wave-uniform -> broadcast
            acc[1] += w * dlds[kk][h * 4 + 1];
            acc[2] += w * dlds[kk][h * 4 + 2];
            acc[3] += w * dlds[kk][h * 4 + 3];
        }
        __syncthreads();
    }
    // LayerNorm over e (128 values spread over waves {wp, wp+1})
    float s[4], q[4];
    #pragma unroll
    for (int rr = 0; rr < 4; ++rr) { s[rr] = acc[rr]; q[rr] = acc[rr] * acc[rr]; }
    #pragma unroll
    for (int off = 32; off; off >>= 1) {
        #pragma unroll
        for (int rr = 0; rr < 4; ++rr) {
            s[rr] += __shfl_xor(s[rr], off);
            q[rr] += __shfl_xor(q[rr], off);
        }
    }
    if (lane == 0) {
        #pragma unroll
        for (int rr = 0; rr < 4; ++rr) { redS[wid][rr] = s[rr]; redQ[wid][rr] = q[rr]; }
    }
    __syncthreads();
    const int wp = h * 2;
    const float ge = gd[e], be = bd[e];
    #pragma unroll
    for (int rr = 0; rr < 4; ++rr) {
        float S = redS[wp][rr] + redS[wp + 1][rr];
        float Q = redQ[wp][rr] + redQ[wp + 1][rr];
        float m = S * (1.f / 128.f);
        float v = Q * (1.f / 128.f) - m * m;
        x[(size_t)(r0 + h * 4 + rr) * 128 + e] = (acc[rr] - m) * rsqrtf(v + EPS) * ge + be;
    }
}

// ---------------- Kernel 2: fused middle -> Zflat ----------------
// sparse: (B,26,64), Ws: (128,64), Wsi: (32,26), x: (B,128), zf: (B,528)
// 8 batch rows per block, 256 threads. Thread (e = t&127, h = t>>7).
__global__ __launch_bounds__(256) void k_middle(
    const float* __restrict__ sparse, const float* __restrict__ Ws,
    const float* __restrict__ gs, const float* __restrict__ bs,
    const float* __restrict__ Wsi, const float* __restrict__ gsi, const float* __restrict__ bsi,
    const float* __restrict__ x, float* __restrict__ zf)
{
    __shared__ float sp[26][64];     // sparse row (broadcast reads)
    __shared__ float T[33][129];     // concat [x; y2^T], padded for gram reads
    __shared__ float y1n[2][128];    // two LN'd y1 columns (n even/odd)
    __shared__ float wsi[32][26];
    __shared__ float redS[4], redQ[4];
    __shared__ float p2[128][2][2];
    const int t = threadIdx.x;
    const int e = t & 127, h = t >> 7;
    const int lane = t & 63, wid = t >> 6;
    const int wp = h * 2;                       // waves {0,1} hold h=0; {2,3} hold h=1
    for (int f = t; f < 32 * 26; f += 256) wsi[f / 26][f % 26] = Wsi[f];
    // Ws row for this thread's e, held in registers (reused across 8 rows / 26 n)
    float w[64];
    #pragma unroll
    for (int d4 = 0; d4 < 16; ++d4) {
        float4 v = *(const float4*)(Ws + e * 64 + d4 * 4);
        w[d4 * 4 + 0] = v.x; w[d4 * 4 + 1] = v.y; w[d4 * 4 + 2] = v.z; w[d4 * 4 + 3] = v.w;
    }
    const float ge = gs[e], be = bs[e];
    for (int g = 0; g < 8; ++g) {
        const size_t row = (size_t)blockIdx.x * 8 + g;
        for (int f = t; f < 26 * 64; f += 256) ((float*)sp)[f] = sparse[row * 1664 + f];
        if (t < 128) T[0][t] = x[row * 128 + t];
        __syncthreads();
        float y2a[16];
        #pragma unroll
        for (int pp = 0; pp < 16; ++pp) y2a[pp] = 0.f;
        // 26 n handled as 13 pairs; thread's half h computes n = 2*np + h
        for (int np = 0; np < 13; ++np) {
            const int n = 2 * np + h;
            float acc = 0.f;
            #pragma unroll
            for (int d = 0; d < 64; d += 4) {
                float4 sv = *(const float4*)(&sp[n][d]);   // wave-broadcast b128
                acc += w[d] * sv.x + w[d + 1] * sv.y + w[d + 2] * sv.z + w[d + 3] * sv.w;
            }
            // LN over e=128 (two waves of same h): wave shuffle + LDS combine
            float s = acc, q = acc * acc;
            #pragma unroll
            for (int off = 32; off; off >>= 1) { s += __shfl_xor(s, off); q += __shfl_xor(q, off); }
            if (lane == 0) { redS[wid] = s; redQ[wid] = q; }
            __syncthreads();
            float S = redS[wp] + redS[wp + 1];
            float Q = redQ[wp] + redQ[wp + 1];
            float m = S * (1.f / 128.f);
            float v = Q * (1.f / 128.f) - m * m;
            y1n[h][e] = (acc - m) * rsqrtf(v + EPS) * ge + be;
            __syncthreads();
            // y2[e][p] += y1[n][e] * Wsi[p][n] for the pair of n
            float ya = y1n[0][e], yb = y1n[1][e];
            #pragma unroll
            for (int pp = 0; pp < 16; ++pp) {
                int p = h * 16 + pp;
                y2a[pp] += ya * wsi[p][2 * np] + yb * wsi[p][2 * np + 1];
            }
        }
        // LN over p=32 (split 16/16 across the thread pair (e,0),(e,1))
        float s2 = 0.f, q2 = 0.f;
        #pragma unroll
        for (int pp = 0; pp < 16; ++pp) { s2 += y2a[pp]; q2 += y2a[pp] * y2a[pp]; }
        p2[e][h][0] = s2; p2[e][h][1] = q2;
        __syncthreads();
        float S = p2[e][0][0] + p2[e][1][0];
        float Q = p2[e][0][1] + p2[e][1][1];
        float m = S * (1.f / 32.f);
        float v = Q * (1.f / 32.f) - m * m;
        float inv = rsqrtf(v + EPS);
        #pragma unroll
        for (int pp = 0; pp < 16; ++pp) {
            int p = h * 16 + pp;
            T[1 + p][e] = (y2a[pp] - m) * inv * gsi[p] + bsi[p];
        }
        __syncthreads();
        // strict lower-tri gram: 528 pairs in np.tril_indices order
        for (int pi = t; pi < 528; pi += 256) {
            int i = (int)((1.f + sqrtf(1.f + 8.f * (float)pi)) * 0.5f);
            while ((i * (i - 1)) / 2 > pi) --i;
            while (((i + 1) * i) / 2 <= pi) ++i;
            int j = pi - (i * (i - 1)) / 2;
            float d = 0.f;
            for (int dd = 0; dd < 128; ++dd) d += T[i][dd] * T[j][dd];
            zf[row * 528 + pi] = d;
        }
        __syncthreads();
    }
}

// ---------------- Kernel 3: out = mask * LN(Zflat @ Wl^T, gl, bl) ----------------
// zf: (B,528), Wl: (512,528), out: (B,512). 32 rows x 512 cols per block.
__global__ __launch_bounds__(256) void k_final(
    const float* __restrict__ zf, const float* __restrict__ Wl,
    const float* __restrict__ gl, const float* __restrict__ bl,
    const int* __restrict__ dims_p, float* __restrict__ out)
{
    __shared__ float wl[512][25];    // Wl K-chunk [c][k], pad 25 -> 2-way (free) aliasing
    __shared__ float zt[24][33];     // Z chunk transposed [k][row]
    __shared__ float red[32][16][2];
    const int t = threadIdx.x;
    const int tx = t & 15, ty = t >> 4;
    const int r0 = blockIdx.x * 32;
    float acc0[32], acc1[32];        // 2 rows x 32 cols (cols = g*64 + tx*4 + s)
    #pragma unroll
    for (int i = 0; i < 32; ++i) { acc0[i] = 0.f; acc1[i] = 0.f; }
    for (int kc = 0; kc < 528; kc += 24) {
        for (int f = t; f < 512 * 24; f += 256) {
            int c = f / 24, kk = f - c * 24;
            wl[c][kk] = Wl[(size_t)c * 528 + kc + kk];
        }
        for (int f = t; f < 32 * 24; f += 256) {
            int r = f / 24, kk = f - r * 24;
            zt[kk][r] = zf[(size_t)(r0 + r) * 528 + kc + kk];
        }
        __syncthreads();
        #pragma unroll
        for (int kk = 0; kk < 24; ++kk) {
            float z0 = zt[kk][ty * 2 + 0], z1 = zt[kk][ty * 2 + 1];
            #pragma unroll
            for (int g = 0; g < 8; ++g) {
                #pragma unroll
                for (int s4 = 0; s4 < 4; ++s4) {
                    float wv = wl[g * 64 + tx * 4 + s4][kk];
                    acc0[g * 4 + s4] += z0 * wv;
                    acc1[g * 4 + s4] += z1 * wv;
                }
            }
        }
        __syncthreads();
    }
    const int dims = dims_p[0];
    // LN over all 512 cols per row (computed BEFORE masking)
    float s0 = 0, q0 = 0, s1 = 0, q1 = 0;
    #pragma unroll
    for (int i = 0; i < 32; ++i) {
        s0 += acc0[i]; q0 += acc0[i] * acc0[i];
        s1 += acc1[i]; q1 += acc1[i] * acc1[i];
    }
    red[ty * 2 + 0][tx][0] = s0; red[ty * 2 + 0][tx][1] = q0;
    red[ty * 2 + 1][tx][0] = s1; red[ty * 2 + 1][tx][1] = q1;
    __syncthreads();
    float S0 = 0, Q0 = 0, S1 = 0, Q1 = 0;
    #pragma unroll
    for (int xx = 0; xx < 16; ++xx) {
        S0 += red[ty * 2 + 0][xx][0]; Q0 += red[ty * 2 + 0][xx][1];
        S1 += red[ty * 2 + 1][xx][0]; Q1 += red[ty * 2 + 1][xx][1];
    }
    float m0 = S0 * (1.f / 512.f), v0 = Q0 * (1.f / 512.f) - m0 * m0, i0 = rsqrtf(v0 + EPS);
    float m1 = S1 * (1.f / 512.f), v1 = Q1 * (1.f / 512.f) - m1 * m1, i1 = rsqrtf(v1 + EPS);
    #pragma unroll
    for (int g = 0; g < 8; ++g) {
        float4 o0, o1;
        float* po0 = (float*)&o0; float* po1 = (float*)&o1;
        #pragma unroll
        for (int s4 = 0; s4 < 4; ++s4) {
            int c = g * 64 + tx * 4 + s4;
            float gg = gl[c], bb = bl[c];
            float r0v = (acc0[g * 4 + s4] - m0) * i0 * gg + bb;
            float r1v = (acc1[g * 4 + s4] - m1) * i1 * gg + bb;
            if (c >= dims) { r0v = 0.f; r1v = 0.f; }
            po0[s4] = r0v; po1[s4] = r1v;
        }
        *(float4*)&out[(size_t)(r0 + ty * 2 + 0) * 512 + g * 64 + tx * 4] = o0;
        *(float4*)&out[(size_t)(r0 + ty * 2 + 1) * 512 + g * 64 + tx * 4] = o1;
    }
}

extern "C" void kernel_launch(void* const* d_in, const int* in_sizes, int n_in,
                              void* d_out, int out_size, void* d_ws, size_t ws_size,
                              hipStream_t stream)
{
    const float* dense  = (const float*)d_in[0];
    const float* sparse = (const float*)d_in[1];
    const float* Wd  = (const float*)d_in[2];
    const float* gd  = (const float*)d_in[3];
    const float* bd  = (const float*)d_in[4];
    const float* Ws  = (const float*)d_in[5];
    const float* gs  = (const float*)d_in[6];
    const float* bs  = (const float*)d_in[7];
    const float* Wsi = (const float*)d_in[8];
    const float* gsi = (const float*)d_in[9];
    const float* bsi = (const float*)d_in[10];
    const float* Wl  = (const float*)d_in[11];
    const float* gl  = (const float*)d_in[12];
    const float* bl  = (const float*)d_in[13];
    const int*   dims = (const int*)d_in[14];
    float* out = (float*)d_out;
    (void)n_in; (void)out_size; (void)ws_size;

    const int B = in_sizes[0] / 256;          // 32768
    float* xw  = (float*)d_ws;                // B*128 floats
    float* zfw = xw + (size_t)B * 128;        // B*528 floats (total ws ~86 MB)

    hipLaunchKernelGGL(k_dense_ln, dim3(B / 8), dim3(256), 0, stream,
                       dense, Wd, gd, bd, xw);
    hipLaunchKernelGGL(k_middle, dim3(B / 8), dim3(256), 0, stream,
                       sparse, Ws, gs, bs, Wsi, gsi, bsi, xw, zfw);
    hipLaunchKernelGGL(k_final, dim3(B / 32), dim3(256), 0, stream,
                       zfw, Wl, gl, bl, dims, out);
}

// Round 3
// 528.340 us; speedup vs baseline: 4.5890x; 4.5890x over previous
//
#include <hip/hip_runtime.h>
#include <math.h>

#define EPS 1e-5f

typedef __attribute__((ext_vector_type(8))) short short8v;   // 8 bf16 (4 VGPR)
typedef __attribute__((ext_vector_type(4))) short short4v;   // 4 bf16
typedef __attribute__((ext_vector_type(4))) float f32x4;

__device__ __forceinline__ short f2bf(float f) {
    union { float f; unsigned u; } v; v.f = f;
    unsigned r = v.u + 0x7FFFu + ((v.u >> 16) & 1u);
    return (short)(r >> 16);
}

// ---------------- prep: convert weights to bf16 (Wsi/Wl zero-padded) ------
__global__ __launch_bounds__(256) void k_prep(
    const float* __restrict__ Ws, const float* __restrict__ Wsi,
    const float* __restrict__ Wl,
    short* __restrict__ wsb, short* __restrict__ wsib, short* __restrict__ wlb)
{
    int i = blockIdx.x * 256 + threadIdx.x;
    if (i < 128 * 64) wsb[i] = f2bf(Ws[i]);
    if (i < 32 * 32) { int p = i >> 5, n = i & 31; wsib[i] = (n < 26) ? f2bf(Wsi[p * 26 + n]) : (short)0; }
    if (i < 512 * 544) { int c = i / 544, k = i - c * 544; wlb[i] = (k < 528) ? f2bf(Wl[c * 528 + k]) : (short)0; }
}

// ---------------- Kernel 1: x = LN(dense @ Wd^T, gd, bd) (unchanged) ------
__global__ __launch_bounds__(256) void k_dense_ln(
    const float* __restrict__ dense, const float* __restrict__ Wd,
    const float* __restrict__ gd, const float* __restrict__ bd,
    float* __restrict__ x)
{
    __shared__ float wlds[128][33];
    __shared__ float dlds[32][9];
    __shared__ float redS[4][4], redQ[4][4];
    const int t = threadIdx.x;
    const int e = t & 127, h = t >> 7;
    const int lane = t & 63, wid = t >> 6;
    const int r0 = blockIdx.x * 8;
    float acc[4] = {0.f, 0.f, 0.f, 0.f};
    for (int kc = 0; kc < 256; kc += 32) {
        for (int f = t; f < 128 * 32; f += 256) {
            int ee = f >> 5, kk = f & 31;
            wlds[ee][kk] = Wd[ee * 256 + kc + kk];
        }
        {
            int rr = t >> 5, kk = t & 31;
            dlds[kk][rr] = dense[(size_t)(r0 + rr) * 256 + kc + kk];
        }
        __syncthreads();
        #pragma unroll
        for (int kk = 0; kk < 32; ++kk) {
            float w = wlds[e][kk];
            acc[0] += w * dlds[kk][h * 4 + 0];
            acc[1] += w * dlds[kk][h * 4 + 1];
            acc[2] += w * dlds[kk][h * 4 + 2];
            acc[3] += w * dlds[kk][h * 4 + 3];
        }
        __syncthreads();
    }
    float s[4], q[4];
    #pragma unroll
    for (int rr = 0; rr < 4; ++rr) { s[rr] = acc[rr]; q[rr] = acc[rr] * acc[rr]; }
    #pragma unroll
    for (int off = 32; off; off >>= 1) {
        #pragma unroll
        for (int rr = 0; rr < 4; ++rr) {
            s[rr] += __shfl_xor(s[rr], off);
            q[rr] += __shfl_xor(q[rr], off);
        }
    }
    if (lane == 0) {
        #pragma unroll
        for (int rr = 0; rr < 4; ++rr) { redS[wid][rr] = s[rr]; redQ[wid][rr] = q[rr]; }
    }
    __syncthreads();
    const int wp = h * 2;
    const float ge = gd[e], be = bd[e];
    #pragma unroll
    for (int rr = 0; rr < 4; ++rr) {
        float S = redS[wp][rr] + redS[wp + 1][rr];
        float Q = redQ[wp][rr] + redQ[wp + 1][rr];
        float m = S * (1.f / 128.f);
        float v = Q * (1.f / 128.f) - m * m;
        x[(size_t)(r0 + h * 4 + rr) * 128 + e] = (acc[rr] - m) * rsqrtf(v + EPS) * ge + be;
    }
}

// ---------------- Kernel 2: fused middle -> Zflat (bf16, padded 544) ------
// 4 batch rows / block, 4 waves (256 thr). Wave w owns row w in phase 5.
// LDS 64,512 B: T overlays y1t (time-sliced; barrier 5 separates).
__global__ __launch_bounds__(256) void k_middle(
    const float* __restrict__ sparse, const short* __restrict__ Wsb,
    const float* __restrict__ gs, const float* __restrict__ bs,
    const short* __restrict__ Wsib, const float* __restrict__ gsi, const float* __restrict__ bsi,
    const float* __restrict__ xw, short* __restrict__ zf)
{
    union U {
        struct {
            short y1t[4][128][40];       // 40960 B  (live: phase 4 .. barrier 5)
            short sp[4][32][72];         // 18432 B  (live: phase 1 .. barrier 2)
            float red[4][4][32][2];      //  4096 B  (live: phase 2 .. barrier 3)
            float minv[4][32][2];        //  1024 B  (live: phase 3 .. barrier 4)
        } P;                             // total 64512 B
        short T[4][33][136];             // 35904 B  (live: after barrier 5; overlays y1t only)
    };
    __shared__ __align__(16) U u;

    const int t = threadIdx.x;
    const int w = t >> 6;            // wave id == batch row within block (phase 5)
    const int l = t & 63;
    const int g = l >> 4;            // lane group
    const int c = l & 15;            // lane-in-group
    const size_t row0 = (size_t)blockIdx.x * 4;

    // ---- phase 1: stage sparse rows as bf16, zero pad rows n=26..31 ----
    for (int f = t; f < 4 * 32 * 16; f += 256) {
        int r = f >> 9;
        int rem = f & 511;
        int n = rem >> 4;
        int d4 = rem & 15;
        short4v o;
        if (n < 26) {
            float4 v = *(const float4*)(sparse + (row0 + r) * 1664 + n * 64 + d4 * 4);
            o[0] = f2bf(v.x); o[1] = f2bf(v.y); o[2] = f2bf(v.z); o[3] = f2bf(v.w);
        } else { o[0] = 0; o[1] = 0; o[2] = 0; o[3] = 0; }
        *(short4v*)(&u.P.sp[r][n][d4 * 4]) = o;
    }
    // Ws B-fragments for this wave's e-range [32w, 32w+32), kept in regs
    short8v bws[2][2];
    #pragma unroll
    for (int nt = 0; nt < 2; ++nt)
        #pragma unroll
        for (int ks = 0; ks < 2; ++ks)
            bws[nt][ks] = *(const short8v*)(Wsb + (32 * w + nt * 16 + c) * 64 + ks * 32 + g * 8);
    __syncthreads();                                          // barrier 1

    // ---- phase 2: stage-A MFMA (y1pre = sparse @ Ws^T), all 4 rows ----
    f32x4 accA[4][2][2];
    #pragma unroll
    for (int r = 0; r < 4; ++r)
        #pragma unroll
        for (int mt = 0; mt < 2; ++mt)
            #pragma unroll
            for (int nt = 0; nt < 2; ++nt)
                accA[r][mt][nt] = (f32x4){0.f, 0.f, 0.f, 0.f};
    #pragma unroll
    for (int r = 0; r < 4; ++r) {
        #pragma unroll
        for (int mt = 0; mt < 2; ++mt) {
            short8v a0 = *(const short8v*)(&u.P.sp[r][mt * 16 + c][g * 8]);
            short8v a1 = *(const short8v*)(&u.P.sp[r][mt * 16 + c][32 + g * 8]);
            #pragma unroll
            for (int nt = 0; nt < 2; ++nt) {
                accA[r][mt][nt] = __builtin_amdgcn_mfma_f32_16x16x32_bf16(a0, bws[nt][0], accA[r][mt][nt], 0, 0, 0);
                accA[r][mt][nt] = __builtin_amdgcn_mfma_f32_16x16x32_bf16(a1, bws[nt][1], accA[r][mt][nt], 0, 0, 0);
            }
        }
    }
    // butterfly partial sums over the 16-lane col group -> red[w][r][n]
    #pragma unroll
    for (int r = 0; r < 4; ++r)
        #pragma unroll
        for (int mt = 0; mt < 2; ++mt)
            #pragma unroll
            for (int reg = 0; reg < 4; ++reg) {
                float v0 = accA[r][mt][0][reg], v1 = accA[r][mt][1][reg];
                float s = v0 + v1, q = v0 * v0 + v1 * v1;
                s += __shfl_xor(s, 1); q += __shfl_xor(q, 1);
                s += __shfl_xor(s, 2); q += __shfl_xor(q, 2);
                s += __shfl_xor(s, 4); q += __shfl_xor(q, 4);
                s += __shfl_xor(s, 8); q += __shfl_xor(q, 8);
                if (c == 0) {
                    int n = mt * 16 + g * 4 + reg;
                    u.P.red[w][r][n][0] = s;
                    u.P.red[w][r][n][1] = q;
                }
            }
    __syncthreads();                                          // barrier 2

    // ---- phase 3: combine across waves -> per-(r,n) mean & inv-std ----
    if (t < 128) {
        int r = t >> 5, n = t & 31;
        float S = 0.f, Q = 0.f;
        #pragma unroll
        for (int ww = 0; ww < 4; ++ww) { S += u.P.red[ww][r][n][0]; Q += u.P.red[ww][r][n][1]; }
        float m = S * (1.f / 128.f);
        float v = Q * (1.f / 128.f) - m * m;
        u.P.minv[r][n][0] = m;
        u.P.minv[r][n][1] = rsqrtf(v + EPS);
    }
    __syncthreads();                                          // barrier 3

    // ---- phase 4: normalize, write y1t transposed [r][e][n] (0 for n>=26) ----
    {
        float ge0 = gs[32 * w + c],      be0 = bs[32 * w + c];
        float ge1 = gs[32 * w + 16 + c], be1 = bs[32 * w + 16 + c];
        #pragma unroll
        for (int r = 0; r < 4; ++r)
            #pragma unroll
            for (int mt = 0; mt < 2; ++mt)
                #pragma unroll
                for (int reg = 0; reg < 4; ++reg) {
                    int n = mt * 16 + g * 4 + reg;
                    float m = u.P.minv[r][n][0], inv = u.P.minv[r][n][1];
                    bool live = (n < 26);
                    float z0 = live ? ((accA[r][mt][0][reg] - m) * inv * ge0 + be0) : 0.f;
                    float z1 = live ? ((accA[r][mt][1][reg] - m) * inv * ge1 + be1) : 0.f;
                    u.P.y1t[r][32 * w + c][n]      = f2bf(z0);
                    u.P.y1t[r][32 * w + 16 + c][n] = f2bf(z1);
                }
    }
    __syncthreads();                                          // barrier 4

    // ---- phase 5a (wave-private): y2 = y1^T @ Wsi^T + LN -> registers ----
    const size_t row = row0 + w;
    float xa = xw[row * 128 + l];
    float xb = xw[row * 128 + 64 + l];
    short8v bwsi0 = *(const short8v*)(Wsib + c * 32 + g * 8);
    short8v bwsi1 = *(const short8v*)(Wsib + (16 + c) * 32 + g * 8);
    short4v tvA[8], tvB[8];
    const float gA = gsi[c], bA = bsi[c];
    const float gB = gsi[16 + c], bB = bsi[16 + c];
    #pragma unroll
    for (int mt = 0; mt < 8; ++mt) {
        short8v af = *(const short8v*)(&u.P.y1t[w][mt * 16 + c][g * 8]);
        f32x4 c0 = (f32x4){0, 0, 0, 0}, c1 = (f32x4){0, 0, 0, 0};
        c0 = __builtin_amdgcn_mfma_f32_16x16x32_bf16(af, bwsi0, c0, 0, 0, 0);
        c1 = __builtin_amdgcn_mfma_f32_16x16x32_bf16(af, bwsi1, c1, 0, 0, 0);
        #pragma unroll
        for (int reg = 0; reg < 4; ++reg) {
            float v0 = c0[reg], v1 = c1[reg];
            float s = v0 + v1, q = v0 * v0 + v1 * v1;
            s += __shfl_xor(s, 1); q += __shfl_xor(q, 1);
            s += __shfl_xor(s, 2); q += __shfl_xor(q, 2);
            s += __shfl_xor(s, 4); q += __shfl_xor(q, 4);
            s += __shfl_xor(s, 8); q += __shfl_xor(q, 8);
            float m = s * (1.f / 32.f);
            float var = q * (1.f / 32.f) - m * m;
            float inv = rsqrtf(var + EPS);
            tvA[mt][reg] = f2bf((v0 - m) * inv * gA + bA);
            tvB[mt][reg] = f2bf((v1 - m) * inv * gB + bB);
        }
    }
    __syncthreads();                     // barrier 5: all y1t reads done; T may now overlay

    // ---- phase 5b: build T = [x ; y2^T] in LDS ----
    u.T[w][0][l]      = f2bf(xa);
    u.T[w][0][64 + l] = f2bf(xb);
    #pragma unroll
    for (int mt = 0; mt < 8; ++mt) {
        *(short4v*)(&u.T[w][1 + c][mt * 16 + g * 4])  = tvA[mt];
        *(short4v*)(&u.T[w][17 + c][mt * 16 + g * 4]) = tvB[mt];
    }
    __syncthreads();                     // barrier 6: fence T writes before gram reads

    // ---- phase 5c: strict-lower gram via MFMA (A/B frags of T coincide) ----
    f32x4 z00 = (f32x4){0,0,0,0}, z10 = (f32x4){0,0,0,0}, z11 = (f32x4){0,0,0,0};
    f32x4 z20 = (f32x4){0,0,0,0}, z21 = (f32x4){0,0,0,0};
    #pragma unroll
    for (int ks = 0; ks < 4; ++ks) {
        short8v f0 = *(const short8v*)(&u.T[w][c][ks * 32 + g * 8]);
        short8v f1 = *(const short8v*)(&u.T[w][16 + c][ks * 32 + g * 8]);
        short8v f2 = *(const short8v*)(&u.T[w][32][ks * 32 + g * 8]);   // only tile-row 0 (i=32) kept
        z00 = __builtin_amdgcn_mfma_f32_16x16x32_bf16(f0, f0, z00, 0, 0, 0);
        z10 = __builtin_amdgcn_mfma_f32_16x16x32_bf16(f1, f0, z10, 0, 0, 0);
        z11 = __builtin_amdgcn_mfma_f32_16x16x32_bf16(f1, f1, z11, 0, 0, 0);
        z20 = __builtin_amdgcn_mfma_f32_16x16x32_bf16(f2, f0, z20, 0, 0, 0);
        z21 = __builtin_amdgcn_mfma_f32_16x16x32_bf16(f2, f1, z21, 0, 0, 0);
    }
    short* zr = zf + row * 544;
    #pragma unroll
    for (int reg = 0; reg < 4; ++reg) {
        int i0 = g * 4 + reg;
        { int i = i0;      int j = c;      if (j < i)  zr[i * (i - 1) / 2 + j] = f2bf(z00[reg]); }
        { int i = 16 + i0; int j = c;                  zr[i * (i - 1) / 2 + j] = f2bf(z10[reg]); }
        { int i = 16 + i0; int j = 16 + c; if (j < i)  zr[i * (i - 1) / 2 + j] = f2bf(z11[reg]); }
        { int i = 32 + i0; int j = c;      if (i < 33) zr[i * (i - 1) / 2 + j] = f2bf(z20[reg]); }
        { int i = 32 + i0; int j = 16 + c; if (i < 33) zr[i * (i - 1) / 2 + j] = f2bf(z21[reg]); }
    }
    if (l < 16) zr[528 + l] = 0;   // zero the K-pad for k_final
}

// ---------------- Kernel 3: out = mask * LN(Zflat @ Wl^T) via MFMA --------
// 32 rows x 512 cols per block, 512 threads (8 waves: 2M x 4N).
__global__ __launch_bounds__(512) void k_final(
    const short* __restrict__ zf, const short* __restrict__ Wlb,
    const float* __restrict__ gl, const float* __restrict__ bl,
    const int* __restrict__ dims_p, float* __restrict__ out)
{
    __shared__ __align__(16) short zlds[32][552];   // 35328 B (all K at once)
    __shared__ __align__(16) short wlds[512][40];   // 40960 B (one 32-K chunk)
    __shared__ float red[32][4][2];                 //  1024 B
    const int t = threadIdx.x;
    const int wv = t >> 6;
    const int l = t & 63;
    const int g = l >> 4, c = l & 15;
    const int wm = wv >> 2;        // 0..1: row half
    const int wn = wv & 3;         // 0..3: col quarter
    const size_t r0 = (size_t)blockIdx.x * 32;

    for (int f = t; f < 32 * 68; f += 512) {
        int r = f / 68, s = f - r * 68;
        *(short8v*)(&zlds[r][s * 8]) = *(const short8v*)(zf + (r0 + r) * 544 + s * 8);
    }
    f32x4 acc[8];
    #pragma unroll
    for (int i = 0; i < 8; ++i) acc[i] = (f32x4){0, 0, 0, 0};
    for (int ks = 0; ks < 17; ++ks) {
        __syncthreads();
        for (int f = t; f < 2048; f += 512) {
            int cc = f >> 2, part = f & 3;
            *(short8v*)(&wlds[cc][part * 8]) = *(const short8v*)(Wlb + cc * 544 + ks * 32 + part * 8);
        }
        __syncthreads();
        short8v af = *(const short8v*)(&zlds[wm * 16 + c][ks * 32 + g * 8]);
        #pragma unroll
        for (int nt = 0; nt < 8; ++nt) {
            short8v bf = *(const short8v*)(&wlds[wn * 128 + nt * 16 + c][g * 8]);
            acc[nt] = __builtin_amdgcn_mfma_f32_16x16x32_bf16(af, bf, acc[nt], 0, 0, 0);
        }
    }
    // LN epilogue over 512 cols per row
    #pragma unroll
    for (int reg = 0; reg < 4; ++reg) {
        float s = 0.f, q = 0.f;
        #pragma unroll
        for (int nt = 0; nt < 8; ++nt) { float v = acc[nt][reg]; s += v; q += v * v; }
        s += __shfl_xor(s, 1); q += __shfl_xor(q, 1);
        s += __shfl_xor(s, 2); q += __shfl_xor(q, 2);
        s += __shfl_xor(s, 4); q += __shfl_xor(q, 4);
        s += __shfl_xor(s, 8); q += __shfl_xor(q, 8);
        if (c == 0) { red[wm * 16 + g * 4 + reg][wn][0] = s; red[wm * 16 + g * 4 + reg][wn][1] = q; }
    }
    __syncthreads();
    const int dims = dims_p[0];
    float M[4], INV[4];
    #pragma unroll
    for (int reg = 0; reg < 4; ++reg) {
        int rr = wm * 16 + g * 4 + reg;
        float S = red[rr][0][0] + red[rr][1][0] + red[rr][2][0] + red[rr][3][0];
        float Q = red[rr][0][1] + red[rr][1][1] + red[rr][2][1] + red[rr][3][1];
        float m = S * (1.f / 512.f);
        float v = Q * (1.f / 512.f) - m * m;
        M[reg] = m; INV[reg] = rsqrtf(v + EPS);
    }
    #pragma unroll
    for (int nt = 0; nt < 8; ++nt) {
        int cc = wn * 128 + nt * 16 + c;
        float gg = (cc < dims) ? gl[cc] : 0.f;
        float bb = (cc < dims) ? bl[cc] : 0.f;
        #pragma unroll
        for (int reg = 0; reg < 4; ++reg) {
            int rr = wm * 16 + g * 4 + reg;
            out[(r0 + rr) * 512 + cc] = (acc[nt][reg] - M[reg]) * INV[reg] * gg + bb;
        }
    }
}

extern "C" void kernel_launch(void* const* d_in, const int* in_sizes, int n_in,
                              void* d_out, int out_size, void* d_ws, size_t ws_size,
                              hipStream_t stream)
{
    const float* dense  = (const float*)d_in[0];
    const float* sparse = (const float*)d_in[1];
    const float* Wd  = (const float*)d_in[2];
    const float* gd  = (const float*)d_in[3];
    const float* bd  = (const float*)d_in[4];
    const float* Ws  = (const float*)d_in[5];
    const float* gs  = (const float*)d_in[6];
    const float* bs  = (const float*)d_in[7];
    const float* Wsi = (const float*)d_in[8];
    const float* gsi = (const float*)d_in[9];
    const float* bsi = (const float*)d_in[10];
    const float* Wl  = (const float*)d_in[11];
    const float* gl  = (const float*)d_in[12];
    const float* bl  = (const float*)d_in[13];
    const int*   dims = (const int*)d_in[14];
    float* out = (float*)d_out;
    (void)n_in; (void)out_size; (void)ws_size;

    const int B = in_sizes[0] / 256;                    // 32768
    // ws layout (bytes): xw f32 | zf_pad bf16 | Ws bf16 | Wsi bf16 pad | Wl bf16 pad
    float* xw  = (float*)d_ws;                          // B*128*4   = 16,777,216
    short* zfw = (short*)((char*)d_ws + (size_t)B * 128 * 4);          // B*544*2
    short* wsb = (short*)((char*)zfw + (size_t)B * 544 * 2);           // 16384 B
    short* wsib = wsb + 128 * 64;                                      // 2048 B
    short* wlb  = wsib + 32 * 32;                                      // 557056 B

    hipLaunchKernelGGL(k_prep, dim3((512 * 544 + 255) / 256), dim3(256), 0, stream,
                       Ws, Wsi, Wl, wsb, wsib, wlb);
    hipLaunchKernelGGL(k_dense_ln, dim3(B / 8), dim3(256), 0, stream,
                       dense, Wd, gd, bd, xw);
    hipLaunchKernelGGL(k_middle, dim3(B / 4), dim3(256), 0, stream,
                       sparse, wsb, gs, bs, wsib, gsi, bsi, xw, zfw);
    hipLaunchKernelGGL(k_final, dim3(B / 32), dim3(512), 0, stream,
                       zfw, wlb, gl, bl, dims, out);
}

// Round 4
// 330.193 us; speedup vs baseline: 7.3428x; 1.6001x over previous
//
#include <hip/hip_runtime.h>
#include <hip/hip_bf16.h>
#include <math.h>

#define EPS 1e-5f

typedef __attribute__((ext_vector_type(8))) short short8v;   // 8 bf16 (4 VGPR)
typedef __attribute__((ext_vector_type(4))) short short4v;   // 4 bf16
typedef __attribute__((ext_vector_type(4))) float f32x4;

__device__ __forceinline__ short f2bf(float f) {
    __hip_bfloat16 h = __float2bfloat16(f);
    return *reinterpret_cast<short*>(&h);
}
__device__ __forceinline__ short8v pack8(float4 a, float4 b) {
    short8v r;
    r[0] = f2bf(a.x); r[1] = f2bf(a.y); r[2] = f2bf(a.z); r[3] = f2bf(a.w);
    r[4] = f2bf(b.x); r[5] = f2bf(b.y); r[6] = f2bf(b.z); r[7] = f2bf(b.w);
    return r;
}

// ---------------- prep: convert weights to bf16 (Wsi/Wl zero-padded) ------
__global__ __launch_bounds__(256) void k_prep(
    const float* __restrict__ Ws, const float* __restrict__ Wsi,
    const float* __restrict__ Wl, const float* __restrict__ Wd,
    short* __restrict__ wsb, short* __restrict__ wsib, short* __restrict__ wlb,
    short* __restrict__ wdb)
{
    int i = blockIdx.x * 256 + threadIdx.x;
    if (i < 128 * 64) wsb[i] = f2bf(Ws[i]);
    if (i < 32 * 32) { int p = i >> 5, n = i & 31; wsib[i] = (n < 26) ? f2bf(Wsi[p * 26 + n]) : (short)0; }
    if (i < 128 * 256) wdb[i] = f2bf(Wd[i]);
    if (i < 512 * 544) { int c = i / 544, k = i - c * 544; wlb[i] = (k < 528) ? f2bf(Wl[c * 528 + k]) : (short)0; }
}

// ---------------- Kernel 1: xbf = LN(dense @ Wd^T) via MFMA, bf16 out ----
// 32 rows x 128 cols per block, 256 thr (4 waves split e: 32 each).
__global__ __launch_bounds__(256) void k_dense_ln(
    const float* __restrict__ dense, const short* __restrict__ wdb,
    const float* __restrict__ gd, const float* __restrict__ bd,
    short* __restrict__ xbf)
{
    __shared__ float red[4][32][2];
    __shared__ float minv[32][2];
    const int t = threadIdx.x;
    const int wv = t >> 6, l = t & 63;
    const int g = l >> 4, c = l & 15;
    const size_t r0 = (size_t)blockIdx.x * 32;

    f32x4 acc[2][2];
    #pragma unroll
    for (int mt = 0; mt < 2; ++mt)
        #pragma unroll
        for (int nt = 0; nt < 2; ++nt) acc[mt][nt] = (f32x4){0.f, 0.f, 0.f, 0.f};

    #pragma unroll
    for (int ks = 0; ks < 8; ++ks) {
        short8v b0 = *(const short8v*)(wdb + (wv * 32 + c) * 256 + ks * 32 + g * 8);
        short8v b1 = *(const short8v*)(wdb + (wv * 32 + 16 + c) * 256 + ks * 32 + g * 8);
        #pragma unroll
        for (int mt = 0; mt < 2; ++mt) {
            const float* p = dense + (r0 + mt * 16 + c) * 256 + ks * 32 + g * 8;
            short8v a = pack8(*(const float4*)p, *(const float4*)(p + 4));
            acc[mt][0] = __builtin_amdgcn_mfma_f32_16x16x32_bf16(a, b0, acc[mt][0], 0, 0, 0);
            acc[mt][1] = __builtin_amdgcn_mfma_f32_16x16x32_bf16(a, b1, acc[mt][1], 0, 0, 0);
        }
    }
    // LN partials over this wave's 32 cols
    #pragma unroll
    for (int mt = 0; mt < 2; ++mt)
        #pragma unroll
        for (int reg = 0; reg < 4; ++reg) {
            float v0 = acc[mt][0][reg], v1 = acc[mt][1][reg];
            float s = v0 + v1, q = v0 * v0 + v1 * v1;
            s += __shfl_xor(s, 1); q += __shfl_xor(q, 1);
            s += __shfl_xor(s, 2); q += __shfl_xor(q, 2);
            s += __shfl_xor(s, 4); q += __shfl_xor(q, 4);
            s += __shfl_xor(s, 8); q += __shfl_xor(q, 8);
            if (c == 0) {
                red[wv][mt * 16 + g * 4 + reg][0] = s;
                red[wv][mt * 16 + g * 4 + reg][1] = q;
            }
        }
    __syncthreads();
    if (t < 32) {
        float S = red[0][t][0] + red[1][t][0] + red[2][t][0] + red[3][t][0];
        float Q = red[0][t][1] + red[1][t][1] + red[2][t][1] + red[3][t][1];
        float m = S * (1.f / 128.f);
        float v = Q * (1.f / 128.f) - m * m;
        minv[t][0] = m; minv[t][1] = rsqrtf(v + EPS);
    }
    __syncthreads();
    const float ge0 = gd[wv * 32 + c],      be0 = bd[wv * 32 + c];
    const float ge1 = gd[wv * 32 + 16 + c], be1 = bd[wv * 32 + 16 + c];
    #pragma unroll
    for (int mt = 0; mt < 2; ++mt)
        #pragma unroll
        for (int reg = 0; reg < 4; ++reg) {
            int rr = mt * 16 + g * 4 + reg;
            float m = minv[rr][0], inv = minv[rr][1];
            xbf[(r0 + rr) * 128 + wv * 32 + c]      = f2bf((acc[mt][0][reg] - m) * inv * ge0 + be0);
            xbf[(r0 + rr) * 128 + wv * 32 + 16 + c] = f2bf((acc[mt][1][reg] - m) * inv * ge1 + be1);
        }
}

// ---------------- Kernel 2: fused middle -> Zflat (wave-independent) ------
// 4 rows / block = 1 row per wave. Per-wave LDS slot (4224 shorts):
//   y1t[e=128][n=32] (offsets 0..4095, XOR-swizzled 16B granules)
//   then overlaid by T[i=33][d=128] (offsets 0..4223, XOR-swizzled)
__global__ __launch_bounds__(256) void k_middle(
    const float* __restrict__ sparse, const short* __restrict__ Wsb,
    const float* __restrict__ gs, const float* __restrict__ bs,
    const short* __restrict__ Wsib, const float* __restrict__ gsi, const float* __restrict__ bsi,
    const short* __restrict__ xbf, short* __restrict__ zf)
{
    __shared__ __align__(16) short lds[4][4224];    // 33792 B total
    const int t = threadIdx.x;
    const int w = t >> 6, l = t & 63;
    const int g = l >> 4, c = l & 15;
    const size_t row = (size_t)blockIdx.x * 4 + w;
    short* W = &lds[w][0];

    // ---- stage A: own-row y1pre = sparse_row @ Ws^T  (M=32n, N=128e, K=64) ----
    short8v afr[2][2];
    #pragma unroll
    for (int mt = 0; mt < 2; ++mt) {
        const int n = mt * 16 + c;
        #pragma unroll
        for (int ks = 0; ks < 2; ++ks) {
            if (n < 26) {
                const float* p = sparse + row * 1664 + n * 64 + ks * 32 + g * 8;
                afr[mt][ks] = pack8(*(const float4*)p, *(const float4*)(p + 4));
            } else {
                afr[mt][ks] = (short8v){0, 0, 0, 0, 0, 0, 0, 0};
            }
        }
    }
    f32x4 acc[2][8];
    #pragma unroll
    for (int mt = 0; mt < 2; ++mt)
        #pragma unroll
        for (int nt = 0; nt < 8; ++nt) acc[mt][nt] = (f32x4){0.f, 0.f, 0.f, 0.f};
    #pragma unroll
    for (int nt = 0; nt < 8; ++nt) {
        short8v b0 = *(const short8v*)(Wsb + (nt * 16 + c) * 64 + g * 8);
        short8v b1 = *(const short8v*)(Wsb + (nt * 16 + c) * 64 + 32 + g * 8);
        #pragma unroll
        for (int mt = 0; mt < 2; ++mt) {
            acc[mt][nt] = __builtin_amdgcn_mfma_f32_16x16x32_bf16(afr[mt][0], b0, acc[mt][nt], 0, 0, 0);
            acc[mt][nt] = __builtin_amdgcn_mfma_f32_16x16x32_bf16(afr[mt][1], b1, acc[mt][nt], 0, 0, 0);
        }
    }
    // ---- LN over e=128, entirely in-wave (nt-sum + c-butterfly) ----
    float ge[8], be[8];
    #pragma unroll
    for (int nt = 0; nt < 8; ++nt) { ge[nt] = gs[nt * 16 + c]; be[nt] = bs[nt * 16 + c]; }
    float m_[2][4], inv_[2][4];
    #pragma unroll
    for (int mt = 0; mt < 2; ++mt)
        #pragma unroll
        for (int reg = 0; reg < 4; ++reg) {
            float s = 0.f, q = 0.f;
            #pragma unroll
            for (int nt = 0; nt < 8; ++nt) { float v = acc[mt][nt][reg]; s += v; q += v * v; }
            s += __shfl_xor(s, 1); q += __shfl_xor(q, 1);
            s += __shfl_xor(s, 2); q += __shfl_xor(q, 2);
            s += __shfl_xor(s, 4); q += __shfl_xor(q, 4);
            s += __shfl_xor(s, 8); q += __shfl_xor(q, 8);
            float m = s * (1.f / 128.f);
            float v = q * (1.f / 128.f) - m * m;
            m_[mt][reg] = m; inv_[mt][reg] = rsqrtf(v + EPS);
        }
    // ---- write y1t[e][n] (bf16, 64B rows, granule swizzle gi ^= (e>>1)&3) ----
    #pragma unroll
    for (int mt = 0; mt < 2; ++mt)
        #pragma unroll
        for (int nt = 0; nt < 8; ++nt) {
            short4v y;
            #pragma unroll
            for (int reg = 0; reg < 4; ++reg) {
                int n = mt * 16 + g * 4 + reg;
                float val = (n < 26) ? ((acc[mt][nt][reg] - m_[mt][reg]) * inv_[mt][reg] * ge[nt] + be[nt]) : 0.f;
                y[reg] = f2bf(val);
            }
            int e = nt * 16 + c;
            int gi = 2 * mt + (g >> 1);
            int off = e * 32 + ((gi ^ ((e >> 1) & 3)) << 3) + (g & 1) * 4;
            *(short4v*)(W + off) = y;
        }
    __syncthreads();

    // ---- stage B: y2 = y1^T @ Wsi^T + LN(p=32) -> registers ----
    short8v bwsi0 = *(const short8v*)(Wsib + c * 32 + g * 8);
    short8v bwsi1 = *(const short8v*)(Wsib + (16 + c) * 32 + g * 8);
    const float gA = gsi[c], bA = bsi[c];
    const float gB = gsi[16 + c], bB = bsi[16 + c];
    short4v tvA[8], tvB[8];
    #pragma unroll
    for (int mt = 0; mt < 8; ++mt) {
        int e = mt * 16 + c;
        short8v af = *(const short8v*)(W + e * 32 + ((g ^ ((e >> 1) & 3)) << 3));
        f32x4 c0 = (f32x4){0, 0, 0, 0}, c1 = (f32x4){0, 0, 0, 0};
        c0 = __builtin_amdgcn_mfma_f32_16x16x32_bf16(af, bwsi0, c0, 0, 0, 0);
        c1 = __builtin_amdgcn_mfma_f32_16x16x32_bf16(af, bwsi1, c1, 0, 0, 0);
        #pragma unroll
        for (int reg = 0; reg < 4; ++reg) {
            float v0 = c0[reg], v1 = c1[reg];
            float s = v0 + v1, q = v0 * v0 + v1 * v1;
            s += __shfl_xor(s, 1); q += __shfl_xor(q, 1);
            s += __shfl_xor(s, 2); q += __shfl_xor(q, 2);
            s += __shfl_xor(s, 4); q += __shfl_xor(q, 4);
            s += __shfl_xor(s, 8); q += __shfl_xor(q, 8);
            float m = s * (1.f / 32.f);
            float var = q * (1.f / 32.f) - m * m;
            float inv = rsqrtf(var + EPS);
            tvA[mt][reg] = f2bf((v0 - m) * inv * gA + bA);
            tvB[mt][reg] = f2bf((v1 - m) * inv * gB + bB);
        }
    }
    __syncthreads();                     // all y1t reads done; T overlays the slot

    // ---- build T = [x ; y2^T] (256B rows, byte-swizzle d ^= (i&7)<<3 in shorts) ----
    if (l < 16) *(short8v*)(W + l * 8) = *(const short8v*)(xbf + row * 128 + l * 8);
    #pragma unroll
    for (int mt = 0; mt < 8; ++mt) {
        { int i = 1 + c;  *(short4v*)(W + i * 128 + ((mt * 16 + g * 4) ^ ((i & 7) << 3))) = tvA[mt]; }
        { int i = 17 + c; *(short4v*)(W + i * 128 + ((mt * 16 + g * 4) ^ ((i & 7) << 3))) = tvB[mt]; }
    }
    __syncthreads();                     // fence T writes before gram reads

    // ---- strict-lower gram via MFMA (A/B frags of T coincide) ----
    f32x4 z00 = (f32x4){0,0,0,0}, z10 = (f32x4){0,0,0,0}, z11 = (f32x4){0,0,0,0};
    f32x4 z20 = (f32x4){0,0,0,0}, z21 = (f32x4){0,0,0,0};
    #pragma unroll
    for (int ks = 0; ks < 4; ++ks) {
        int d = ks * 32 + g * 8;
        short8v f0 = *(const short8v*)(W + c * 128 + (d ^ ((c & 7) << 3)));
        short8v f1 = *(const short8v*)(W + (16 + c) * 128 + (d ^ ((c & 7) << 3)));
        short8v f2 = *(const short8v*)(W + 32 * 128 + d);
        z00 = __builtin_amdgcn_mfma_f32_16x16x32_bf16(f0, f0, z00, 0, 0, 0);
        z10 = __builtin_amdgcn_mfma_f32_16x16x32_bf16(f1, f0, z10, 0, 0, 0);
        z11 = __builtin_amdgcn_mfma_f32_16x16x32_bf16(f1, f1, z11, 0, 0, 0);
        z20 = __builtin_amdgcn_mfma_f32_16x16x32_bf16(f2, f0, z20, 0, 0, 0);
        z21 = __builtin_amdgcn_mfma_f32_16x16x32_bf16(f2, f1, z21, 0, 0, 0);
    }
    short* zr = zf + row * 544;
    #pragma unroll
    for (int reg = 0; reg < 4; ++reg) {
        int i0 = g * 4 + reg;
        { int i = i0;      int j = c;      if (j < i)  zr[i * (i - 1) / 2 + j] = f2bf(z00[reg]); }
        { int i = 16 + i0; int j = c;                  zr[i * (i - 1) / 2 + j] = f2bf(z10[reg]); }
        { int i = 16 + i0; int j = 16 + c; if (j < i)  zr[i * (i - 1) / 2 + j] = f2bf(z11[reg]); }
        { int i = 32 + i0; int j = c;      if (i < 33) zr[i * (i - 1) / 2 + j] = f2bf(z20[reg]); }
        { int i = 32 + i0; int j = 16 + c; if (i < 33) zr[i * (i - 1) / 2 + j] = f2bf(z21[reg]); }
    }
    if (l < 16) zr[528 + l] = 0;   // zero the K-pad for k_final
}

// ---------------- Kernel 3: out = mask * LN(Zflat @ Wl^T) via MFMA --------
// 32 rows x 512 cols per block, 512 threads (8 waves: 2M x 4N).
__global__ __launch_bounds__(512) void k_final(
    const short* __restrict__ zf, const short* __restrict__ Wlb,
    const float* __restrict__ gl, const float* __restrict__ bl,
    const int* __restrict__ dims_p, float* __restrict__ out)
{
    __shared__ __align__(16) short zlds[32][552];   // 35328 B (all K at once)
    __shared__ __align__(16) short wlds[512][40];   // 40960 B (one 32-K chunk)
    __shared__ float red[32][4][2];                 //  1024 B
    const int t = threadIdx.x;
    const int wv = t >> 6;
    const int l = t & 63;
    const int g = l >> 4, c = l & 15;
    const int wm = wv >> 2;        // 0..1: row half
    const int wn = wv & 3;         // 0..3: col quarter
    const size_t r0 = (size_t)blockIdx.x * 32;

    for (int f = t; f < 32 * 68; f += 512) {
        int r = f / 68, s = f - r * 68;
        *(short8v*)(&zlds[r][s * 8]) = *(const short8v*)(zf + (r0 + r) * 544 + s * 8);
    }
    f32x4 acc[8];
    #pragma unroll
    for (int i = 0; i < 8; ++i) acc[i] = (f32x4){0, 0, 0, 0};
    for (int ks = 0; ks < 17; ++ks) {
        __syncthreads();
        for (int f = t; f < 2048; f += 512) {
            int cc = f >> 2, part = f & 3;
            *(short8v*)(&wlds[cc][part * 8]) = *(const short8v*)(Wlb + cc * 544 + ks * 32 + part * 8);
        }
        __syncthreads();
        short8v af = *(const short8v*)(&zlds[wm * 16 + c][ks * 32 + g * 8]);
        #pragma unroll
        for (int nt = 0; nt < 8; ++nt) {
            short8v bf = *(const short8v*)(&wlds[wn * 128 + nt * 16 + c][g * 8]);
            acc[nt] = __builtin_amdgcn_mfma_f32_16x16x32_bf16(af, bf, acc[nt], 0, 0, 0);
        }
    }
    // LN epilogue over 512 cols per row
    #pragma unroll
    for (int reg = 0; reg < 4; ++reg) {
        float s = 0.f, q = 0.f;
        #pragma unroll
        for (int nt = 0; nt < 8; ++nt) { float v = acc[nt][reg]; s += v; q += v * v; }
        s += __shfl_xor(s, 1); q += __shfl_xor(q, 1);
        s += __shfl_xor(s, 2); q += __shfl_xor(q, 2);
        s += __shfl_xor(s, 4); q += __shfl_xor(q, 4);
        s += __shfl_xor(s, 8); q += __shfl_xor(q, 8);
        if (c == 0) { red[wm * 16 + g * 4 + reg][wn][0] = s; red[wm * 16 + g * 4 + reg][wn][1] = q; }
    }
    __syncthreads();
    const int dims = dims_p[0];
    float M[4], INV[4];
    #pragma unroll
    for (int reg = 0; reg < 4; ++reg) {
        int rr = wm * 16 + g * 4 + reg;
        float S = red[rr][0][0] + red[rr][1][0] + red[rr][2][0] + red[rr][3][0];
        float Q = red[rr][0][1] + red[rr][1][1] + red[rr][2][1] + red[rr][3][1];
        float m = S * (1.f / 512.f);
        float v = Q * (1.f / 512.f) - m * m;
        M[reg] = m; INV[reg] = rsqrtf(v + EPS);
    }
    #pragma unroll
    for (int nt = 0; nt < 8; ++nt) {
        int cc = wn * 128 + nt * 16 + c;
        float gg = (cc < dims) ? gl[cc] : 0.f;
        float bb = (cc < dims) ? bl[cc] : 0.f;
        #pragma unroll
        for (int reg = 0; reg < 4; ++reg) {
            int rr = wm * 16 + g * 4 + reg;
            out[(r0 + rr) * 512 + cc] = (acc[nt][reg] - M[reg]) * INV[reg] * gg + bb;
        }
    }
}

extern "C" void kernel_launch(void* const* d_in, const int* in_sizes, int n_in,
                              void* d_out, int out_size, void* d_ws, size_t ws_size,
                              hipStream_t stream)
{
    const float* dense  = (const float*)d_in[0];
    const float* sparse = (const float*)d_in[1];
    const float* Wd  = (const float*)d_in[2];
    const float* gd  = (const float*)d_in[3];
    const float* bd  = (const float*)d_in[4];
    const float* Ws  = (const float*)d_in[5];
    const float* gs  = (const float*)d_in[6];
    const float* bs  = (const float*)d_in[7];
    const float* Wsi = (const float*)d_in[8];
    const float* gsi = (const float*)d_in[9];
    const float* bsi = (const float*)d_in[10];
    const float* Wl  = (const float*)d_in[11];
    const float* gl  = (const float*)d_in[12];
    const float* bl  = (const float*)d_in[13];
    const int*   dims = (const int*)d_in[14];
    float* out = (float*)d_out;
    (void)n_in; (void)out_size; (void)ws_size;

    const int B = in_sizes[0] / 256;                    // 32768
    // ws layout: xbf bf16 | zf bf16(pad544) | wsb | wsib | wlb | wdb
    short* xbf = (short*)d_ws;                                         // B*128*2
    short* zfw = xbf + (size_t)B * 128;                                // B*544*2
    short* wsb = zfw + (size_t)B * 544;                                // 16384 B
    short* wsib = wsb + 128 * 64;                                      // 2048 B
    short* wlb  = wsib + 32 * 32;                                      // 557056 B
    short* wdb  = wlb + 512 * 544;                                     // 65536 B

    hipLaunchKernelGGL(k_prep, dim3(1088), dim3(256), 0, stream,
                       Ws, Wsi, Wl, Wd, wsb, wsib, wlb, wdb);
    hipLaunchKernelGGL(k_dense_ln, dim3(B / 32), dim3(256), 0, stream,
                       dense, wdb, gd, bd, xbf);
    hipLaunchKernelGGL(k_middle, dim3(B / 4), dim3(256), 0, stream,
                       sparse, wsb, gs, bs, wsib, gsi, bsi, xbf, zfw);
    hipLaunchKernelGGL(k_final, dim3(B / 32), dim3(512), 0, stream,
                       zfw, wlb, gl, bl, dims, out);
}